// Round 2
// baseline (17166.904 us; speedup 1.0000x reference)
//
#include <hip/hip_runtime.h>

#define H_DIM 256
#define NLAYER 5
#define BGRAPH 1024

// ---- bf16 helpers (storage-only; all math fp32) ----
struct __align__(8) us4 { unsigned short x, y, z, w; };

__device__ __forceinline__ float b2f(unsigned short u) {
    union { float f; unsigned v; } c; c.v = ((unsigned)u) << 16; return c.f;
}
__device__ __forceinline__ unsigned short f2b(float f) {
    union { float f; unsigned v; } c; c.f = f;
    return (unsigned short)((c.v + 0x7fffu + ((c.v >> 16) & 1u)) >> 16);
}

// ---------------------------------------------------------------- embed ----
// h[m,n] = sum_k x[m,k] * W[k,n] + b[n]; 8 rows/block, 256 threads (n)
__global__ __launch_bounds__(256) void embed_kernel(
    const float* __restrict__ x, const float* __restrict__ W,
    const float* __restrict__ b, unsigned short* __restrict__ h, int K)
{
    __shared__ float xs[256];            // 8 rows * K (K <= 32)
    const int m0 = blockIdx.x * 8;
    const int tid = threadIdx.x;
    if (tid < 8 * K) xs[tid] = x[(size_t)m0 * K + tid];
    __syncthreads();
    const int n = tid;
    float acc[8] = {0.f,0.f,0.f,0.f,0.f,0.f,0.f,0.f};
    for (int k = 0; k < K; ++k) {
        const float w = W[k * H_DIM + n];
        #pragma unroll
        for (int r = 0; r < 8; ++r) acc[r] += xs[r * K + k] * w;
    }
    const float bb = b[n];
    #pragma unroll
    for (int r = 0; r < 8; ++r)
        h[(size_t)(m0 + r) * H_DIM + n] = f2b(acc[r] + bb);
}

// ---------------------------------------------------------------- init v ---
__global__ __launch_bounds__(256) void init_v_kernel(
    const float* __restrict__ lig0, const float* __restrict__ prot0,
    float* __restrict__ lig_v, float* __restrict__ prot_v)
{
    const int b = blockIdx.x, n = threadIdx.x;
    lig_v[b * H_DIM + n]  = lig0[n];
    prot_v[b * H_DIM + n] = prot0[n];
}

// ------------------------------------------------------------ pool (v+=) ---
__global__ __launch_bounds__(256) void pool_add_kernel(
    const unsigned short* __restrict__ h, float* __restrict__ v, int cnt)
{
    const int b = blockIdx.x, n = threadIdx.x;
    const unsigned short* hp = &h[(size_t)b * cnt * H_DIM + n];
    float s = 0.f;
    #pragma unroll 8
    for (int r = 0; r < cnt; ++r) s += b2f(hp[(size_t)r * H_DIM]);
    v[b * H_DIM + n] += s;
}

// ----------------------------------------------------- small fp32 GEMM -----
// C[M,N] = op(A[M,K] @ W[K,N] + bias); BM=32, BN=64, BK=32, 256 threads
template<bool RELU>
__global__ __launch_bounds__(256) void gemm_small_kernel(
    const float* __restrict__ A, const float* __restrict__ W,
    const float* __restrict__ bias, float* __restrict__ C,
    int M, int N, int K)
{
    constexpr int BM = 32, BN = 64, BK = 32, TM = 2;
    __shared__ __align__(16) float As[BK][BM + 4];
    __shared__ __align__(16) float Bs[BK][BN];
    const int tid = threadIdx.x;
    const int tx = tid & 15;    // 4 cols
    const int ty = tid >> 4;    // TM rows
    const int m0 = blockIdx.x * BM;
    const int n0 = blockIdx.y * BN;

    float acc[TM][4] = {};

    for (int kt = 0; kt < K; kt += BK) {
        {   // A tile: 32 rows x 32 k = 256 float4
            const int row = tid >> 3, kq = tid & 7;
            const float4 a = *(const float4*)&A[(size_t)(m0 + row) * K + kt + kq * 4];
            As[kq * 4 + 0][row] = a.x;
            As[kq * 4 + 1][row] = a.y;
            As[kq * 4 + 2][row] = a.z;
            As[kq * 4 + 3][row] = a.w;
        }
        #pragma unroll
        for (int i = 0; i < 2; ++i) {   // B tile: 32 x 64 = 512 float4
            const int f = tid + i * 256;
            const int row = f >> 4, c4 = f & 15;
            *(float4*)&Bs[row][c4 * 4] =
                *(const float4*)&W[(size_t)(kt + row) * N + n0 + c4 * 4];
        }
        __syncthreads();
        #pragma unroll
        for (int kk = 0; kk < BK; ++kk) {
            const float4 bv = *(const float4*)&Bs[kk][tx * 4];
            #pragma unroll
            for (int im = 0; im < TM; ++im) {
                const float a = As[kk][ty * TM + im];
                acc[im][0] += a * bv.x; acc[im][1] += a * bv.y;
                acc[im][2] += a * bv.z; acc[im][3] += a * bv.w;
            }
        }
        __syncthreads();
    }

    const float4 bb = *(const float4*)&bias[n0 + tx * 4];
    #pragma unroll
    for (int im = 0; im < TM; ++im) {
        const int m = m0 + ty * TM + im;
        float4 r;
        r.x = acc[im][0] + bb.x; r.y = acc[im][1] + bb.y;
        r.z = acc[im][2] + bb.z; r.w = acc[im][3] + bb.w;
        if constexpr (RELU) {
            r.x = fmaxf(r.x, 0.f); r.y = fmaxf(r.y, 0.f);
            r.z = fmaxf(r.z, 0.f); r.w = fmaxf(r.w, 0.f);
        }
        *(float4*)&C[(size_t)m * N + n0 + tx * 4] = r;
    }
}

// ------------------------------------------------------------ conv GEMM ----
// BM=64, BN=256(full width), BK=32, 512 threads.
// GEMM1: Z = relu(Z @ W + b)        (in place; block owns its row stripe)
// GEMM2: Hb(bf16) += Z @ W + b
template<bool GEMM1>
__global__ __launch_bounds__(512) void conv_gemm_kernel(
    float* __restrict__ Z, const float* __restrict__ W,
    const float* __restrict__ bias, unsigned short* __restrict__ Hb)
{
    constexpr int BM = 64, BK = 32, K = H_DIM;
    __shared__ __align__(16) float As[BK][BM + 4];
    __shared__ __align__(16) float Bs[BK][H_DIM];
    const int tid = threadIdx.x;
    const int tx = tid & 63;    // 4 cols each (64*4 = 256)
    const int ty = tid >> 6;    // 8 rows each (8*8 = 64)
    const int m0 = blockIdx.x * BM;

    float acc[8][4] = {};

    for (int kt = 0; kt < K; kt += BK) {
        {   // A: 64 rows x 32 k = 512 float4, one per thread
            const int row = tid >> 3, kq = tid & 7;
            const float4 a = *(const float4*)&Z[(size_t)(m0 + row) * K + kt + kq * 4];
            As[kq * 4 + 0][row] = a.x;
            As[kq * 4 + 1][row] = a.y;
            As[kq * 4 + 2][row] = a.z;
            As[kq * 4 + 3][row] = a.w;
        }
        #pragma unroll
        for (int i = 0; i < 4; ++i) {   // B: 32 x 256 = 2048 float4
            const int f = tid + i * 512;
            const int row = f >> 6, c4 = f & 63;
            *(float4*)&Bs[row][c4 * 4] =
                *(const float4*)&W[(size_t)(kt + row) * H_DIM + c4 * 4];
        }
        __syncthreads();
        #pragma unroll
        for (int kk = 0; kk < BK; ++kk) {
            const float4 bv = *(const float4*)&Bs[kk][tx * 4];
            float a[8];
            *(float4*)&a[0] = *(const float4*)&As[kk][ty * 8];
            *(float4*)&a[4] = *(const float4*)&As[kk][ty * 8 + 4];
            #pragma unroll
            for (int im = 0; im < 8; ++im) {
                acc[im][0] += a[im] * bv.x; acc[im][1] += a[im] * bv.y;
                acc[im][2] += a[im] * bv.z; acc[im][3] += a[im] * bv.w;
            }
        }
        __syncthreads();
    }

    const float4 bb = *(const float4*)&bias[tx * 4];
    #pragma unroll
    for (int im = 0; im < 8; ++im) {
        const int m = m0 + ty * 8 + im;
        float4 r;
        r.x = acc[im][0] + bb.x; r.y = acc[im][1] + bb.y;
        r.z = acc[im][2] + bb.z; r.w = acc[im][3] + bb.w;
        if constexpr (GEMM1) {
            r.x = fmaxf(r.x, 0.f); r.y = fmaxf(r.y, 0.f);
            r.z = fmaxf(r.z, 0.f); r.w = fmaxf(r.w, 0.f);
            *(float4*)&Z[(size_t)m * H_DIM + tx * 4] = r;
        } else {
            us4* hp = (us4*)&Hb[(size_t)m * H_DIM + tx * 4];
            const us4 old = *hp;
            us4 o;
            o.x = f2b(b2f(old.x) + r.x); o.y = f2b(b2f(old.y) + r.y);
            o.z = f2b(b2f(old.z) + r.z); o.w = f2b(b2f(old.w) + r.w);
            *hp = o;
        }
    }
}

// ------------------------------------------------------------- BN stats ----
__global__ __launch_bounds__(1024) void bn_stats_kernel(
    const float* __restrict__ vtmp, const float* __restrict__ gamma,
    const float* __restrict__ beta, float* __restrict__ scale,
    float* __restrict__ shift)
{
    __shared__ float ssum[4][256];
    __shared__ float ssq[4][256];
    const int n = threadIdx.x & 255;
    const int g = threadIdx.x >> 8;
    float s = 0.f, s2 = 0.f;
    #pragma unroll 8
    for (int r = g; r < BGRAPH; r += 4) {
        const float x = vtmp[(size_t)r * H_DIM + n];
        s += x; s2 += x * x;
    }
    ssum[g][n] = s; ssq[g][n] = s2;
    __syncthreads();
    if (g == 0) {
        s  = ssum[0][n] + ssum[1][n] + ssum[2][n] + ssum[3][n];
        s2 = ssq[0][n]  + ssq[1][n]  + ssq[2][n]  + ssq[3][n];
        const float mean = s * (1.f / BGRAPH);
        const float var  = s2 * (1.f / BGRAPH) - mean * mean;
        const float inv  = rsqrtf(var + 1e-5f);
        const float sc   = gamma[n] * inv;
        scale[n] = sc;
        shift[n] = beta[n] - mean * sc;
    }
}

// -------------------------------------------------------------- BN relu ----
__global__ __launch_bounds__(256) void bn_relu_kernel(
    const float* __restrict__ vtmp, const float* __restrict__ scale,
    const float* __restrict__ shift, float* __restrict__ v)
{
    const int idx = blockIdx.x * 256 + threadIdx.x;
    const int n = idx & 255;
    v[idx] = fmaxf(vtmp[idx] * scale[n] + shift[n], 0.f);
}

// ------------------------------------- h(bf16) += v[batch]; z(f32) = h -----
__global__ __launch_bounds__(256) void h_update_kernel(
    unsigned short* __restrict__ h, float* __restrict__ z,
    const float* __restrict__ v, const int* __restrict__ batch)
{
    const size_t i4 = (size_t)blockIdx.x * 256 + threadIdx.x;  // 4-elem group
    const int m = (int)(i4 >> 6);
    const int b = batch[m];
    const us4 hv = ((const us4*)h)[i4];
    const float4 vv = ((const float4*)v)[(size_t)b * 64 + (i4 & 63)];
    us4 o;
    o.x = f2b(b2f(hv.x) + vv.x); o.y = f2b(b2f(hv.y) + vv.y);
    o.z = f2b(b2f(hv.z) + vv.z); o.w = f2b(b2f(hv.w) + vv.w);
    ((us4*)h)[i4] = o;
    float4 zr = { b2f(o.x), b2f(o.y), b2f(o.z), b2f(o.w) };
    ((float4*)z)[i4] = zr;
}

// --------------------------------------------------------- edge scatter ----
// z[dst[e], :] += h[src[e], :]   (one wave per edge, 4 elems per lane)
__global__ __launch_bounds__(256) void scatter_add_kernel(
    const int* __restrict__ src, const int* __restrict__ dst,
    const unsigned short* __restrict__ h, float* __restrict__ z)
{
    const int e = blockIdx.x * 4 + (threadIdx.x >> 6);
    const int lane = threadIdx.x & 63;
    const int s = src[e], d = dst[e];
    const us4 hv = *(const us4*)&h[(size_t)s * H_DIM + lane * 4];
    float* zp = &z[(size_t)d * H_DIM + lane * 4];
    atomicAdd(zp + 0, b2f(hv.x));
    atomicAdd(zp + 1, b2f(hv.y));
    atomicAdd(zp + 2, b2f(hv.z));
    atomicAdd(zp + 3, b2f(hv.w));
}

// ----------------------------------------------------- final mean pools ----
__global__ __launch_bounds__(256) void pool_final_kernel(
    const unsigned short* __restrict__ lig_h,
    const unsigned short* __restrict__ prot_h, float* __restrict__ comb)
{
    const int b = blockIdx.x, n = threadIdx.x;
    float s = 0.f;
    #pragma unroll 8
    for (int r = 0; r < 64; ++r) s += b2f(lig_h[(size_t)(b * 64 + r) * H_DIM + n]);
    comb[(size_t)b * 512 + n] = s * (1.f / 64.f);
    float s2 = 0.f;
    #pragma unroll 8
    for (int r = 0; r < 128; ++r) s2 += b2f(prot_h[(size_t)(b * 128 + r) * H_DIM + n]);
    comb[(size_t)b * 512 + 256 + n] = s2 * (1.f / 128.f);
}

// ------------------------------------------------------------ final dot ----
__global__ __launch_bounds__(256) void pred_final_kernel(
    const float* __restrict__ hidden, const float* __restrict__ W2,
    const float* __restrict__ b2, float* __restrict__ out)
{
    const int b = blockIdx.x, t = threadIdx.x;
    float p = hidden[(size_t)b * H_DIM + t] * W2[t];
    #pragma unroll
    for (int off = 32; off >= 1; off >>= 1) p += __shfl_down(p, off);
    __shared__ float red[4];
    if ((t & 63) == 0) red[t >> 6] = p;
    __syncthreads();
    if (t == 0) out[b] = red[0] + red[1] + red[2] + red[3] + b2[0];
}

// ===========================================================================
extern "C" void kernel_launch(void* const* d_in, const int* in_sizes, int n_in,
                              void* d_out, int out_size, void* d_ws, size_t ws_size,
                              hipStream_t stream)
{
    const int NL = 65536, NP = 131072, EL = 262144, EP = 524288;
    const int B = BGRAPH, H = H_DIM;

    const float* lig_x        = (const float*)d_in[0];
    const float* prot_x       = (const float*)d_in[1];
    const float* lig_embed_W  = (const float*)d_in[2];
    const float* lig_embed_b  = (const float*)d_in[3];
    const float* prot_embed_W = (const float*)d_in[4];
    const float* prot_embed_b = (const float*)d_in[5];
    const float* lig_virtual0 = (const float*)d_in[6];
    const float* prot_virtual0= (const float*)d_in[7];
    const float* lig_conv_W1  = (const float*)d_in[8];
    const float* lig_conv_b1  = (const float*)d_in[9];
    const float* lig_conv_W2  = (const float*)d_in[10];
    const float* lig_conv_b2  = (const float*)d_in[11];
    const float* lig_vmlp_W   = (const float*)d_in[12];
    const float* lig_vmlp_b   = (const float*)d_in[13];
    const float* lig_vmlp_g   = (const float*)d_in[14];
    const float* lig_vmlp_be  = (const float*)d_in[15];
    const float* prot_conv_W1 = (const float*)d_in[16];
    const float* prot_conv_b1 = (const float*)d_in[17];
    const float* prot_conv_W2 = (const float*)d_in[18];
    const float* prot_conv_b2 = (const float*)d_in[19];
    const float* prot_vmlp_W  = (const float*)d_in[20];
    const float* prot_vmlp_b  = (const float*)d_in[21];
    const float* prot_vmlp_g  = (const float*)d_in[22];
    const float* prot_vmlp_be = (const float*)d_in[23];
    const float* pred_W1      = (const float*)d_in[24];
    const float* pred_b1      = (const float*)d_in[25];
    const float* pred_W2      = (const float*)d_in[26];
    const float* pred_b2      = (const float*)d_in[27];
    const int* lig_batch      = (const int*)d_in[28];
    const int* prot_batch     = (const int*)d_in[29];
    const int* lig_ei         = (const int*)d_in[30];
    const int* prot_ei        = (const int*)d_in[31];

    // ---- workspace layout (~230 MB) ----
    float* ws = (float*)d_ws;
    float* zbuf   = ws;                        // NP*H f32 (shared lig/prot)
    float* lig_v  = zbuf   + (size_t)NP * H;   // B*H
    float* prot_v = lig_v  + (size_t)B * H;    // B*H
    float* vtmp   = prot_v + (size_t)B * H;    // B*H
    float* scale  = vtmp   + (size_t)B * H;    // H
    float* shift  = scale  + H;                // H
    float* comb   = shift  + H;                // B*2H
    float* hidden = comb   + (size_t)B * 2 * H;// B*H
    unsigned short* lig_h  = (unsigned short*)(hidden + (size_t)B * H); // NL*H bf16
    unsigned short* prot_h = lig_h + (size_t)NL * H;                    // NP*H bf16

    // ---- embeddings ----
    embed_kernel<<<NL / 8, 256, 0, stream>>>(lig_x, lig_embed_W, lig_embed_b, lig_h, 26);
    embed_kernel<<<NP / 8, 256, 0, stream>>>(prot_x, prot_embed_W, prot_embed_b, prot_h, 20);
    init_v_kernel<<<B, 256, 0, stream>>>(lig_virtual0, prot_virtual0, lig_v, prot_v);

    auto layer = [&](unsigned short* h, int Nn, int cnt, float* v,
                     const float* vW, const float* vb, const float* vg, const float* vbe,
                     const float* W1, const float* b1, const float* W2, const float* b2,
                     const int* batch, const int* ei, int E) {
        pool_add_kernel<<<B, 256, 0, stream>>>(h, v, cnt);
        gemm_small_kernel<false><<<dim3(B / 32, 4), 256, 0, stream>>>(
            v, vW, vb, vtmp, B, H, H);
        bn_stats_kernel<<<1, 1024, 0, stream>>>(vtmp, vg, vbe, scale, shift);
        bn_relu_kernel<<<B, 256, 0, stream>>>(vtmp, scale, shift, v);
        h_update_kernel<<<Nn / 4, 256, 0, stream>>>(h, zbuf, v, batch);
        scatter_add_kernel<<<E / 4, 256, 0, stream>>>(ei, ei + E, h, zbuf);
        conv_gemm_kernel<true><<<Nn / 64, 512, 0, stream>>>(zbuf, W1, b1, nullptr);
        conv_gemm_kernel<false><<<Nn / 64, 512, 0, stream>>>(zbuf, W2, b2, h);
    };

    for (int i = 0; i < NLAYER; ++i) {
        const size_t wo = (size_t)i * H * H;
        const size_t bo = (size_t)i * H;
        layer(lig_h, NL, 64, lig_v,
              lig_vmlp_W + wo, lig_vmlp_b + bo, lig_vmlp_g + bo, lig_vmlp_be + bo,
              lig_conv_W1 + wo, lig_conv_b1 + bo, lig_conv_W2 + wo, lig_conv_b2 + bo,
              lig_batch, lig_ei, EL);
        layer(prot_h, NP, 128, prot_v,
              prot_vmlp_W + wo, prot_vmlp_b + bo, prot_vmlp_g + bo, prot_vmlp_be + bo,
              prot_conv_W1 + wo, prot_conv_b1 + bo, prot_conv_W2 + wo, prot_conv_b2 + bo,
              prot_batch, prot_ei, EP);
    }

    // ---- readout ----
    pool_final_kernel<<<B, 256, 0, stream>>>(lig_h, prot_h, comb);
    gemm_small_kernel<true><<<dim3(B / 32, 4), 256, 0, stream>>>(
        comb, pred_W1, pred_b1, hidden, B, H, 2 * H);
    pred_final_kernel<<<B, 256, 0, stream>>>(hidden, pred_W2, pred_b2, (float*)d_out);
}

// Round 3
// 4633.684 us; speedup vs baseline: 3.7048x; 3.7048x over previous
//
#include <hip/hip_runtime.h>

#define H_DIM 256
#define NLAYER 5
#define BGRAPH 1024
#define CAP 16
#define OVF_CAP 4096

// ---- bf16 helpers (storage-only; all math fp32) ----
struct __align__(8) us4 { unsigned short x, y, z, w; };

__device__ __forceinline__ float b2f(unsigned short u) {
    union { float f; unsigned v; } c; c.v = ((unsigned)u) << 16; return c.f;
}
__device__ __forceinline__ unsigned short f2b(float f) {
    union { float f; unsigned v; } c; c.f = f;
    return (unsigned short)((c.v + 0x7fffu + ((c.v >> 16) & 1u)) >> 16);
}

// ---------------------------------------------------------------- embed ----
__global__ __launch_bounds__(256) void embed_kernel(
    const float* __restrict__ x, const float* __restrict__ W,
    const float* __restrict__ b, unsigned short* __restrict__ h, int K)
{
    __shared__ float xs[256];            // 8 rows * K (K <= 32)
    const int m0 = blockIdx.x * 8;
    const int tid = threadIdx.x;
    if (tid < 8 * K) xs[tid] = x[(size_t)m0 * K + tid];
    __syncthreads();
    const int n = tid;
    float acc[8] = {0.f,0.f,0.f,0.f,0.f,0.f,0.f,0.f};
    for (int k = 0; k < K; ++k) {
        const float w = W[k * H_DIM + n];
        #pragma unroll
        for (int r = 0; r < 8; ++r) acc[r] += xs[r * K + k] * w;
    }
    const float bb = b[n];
    #pragma unroll
    for (int r = 0; r < 8; ++r)
        h[(size_t)(m0 + r) * H_DIM + n] = f2b(acc[r] + bb);
}

// ---------------------------------------------------------------- init v ---
__global__ __launch_bounds__(256) void init_v_kernel(
    const float* __restrict__ lig0, const float* __restrict__ prot0,
    float* __restrict__ lig_v, float* __restrict__ prot_v)
{
    const int b = blockIdx.x, n = threadIdx.x;
    lig_v[b * H_DIM + n]  = lig0[n];
    prot_v[b * H_DIM + n] = prot0[n];
}

// ------------------------------------------------------- bucket build ------
// deg[d]++ ; bucket[d][slot] = src ; overflow -> list (applied with atomics)
__global__ __launch_bounds__(256) void bucket_build_kernel(
    const int* __restrict__ src, const int* __restrict__ dst, int E,
    int* __restrict__ deg, int* __restrict__ bucket,
    int* __restrict__ ovf, int* __restrict__ ovf_cnt)
{
    const int e = blockIdx.x * 256 + threadIdx.x;
    if (e >= E) return;
    const int d = dst[e], s = src[e];
    const int slot = atomicAdd(&deg[d], 1);
    if (slot < CAP) {
        bucket[(size_t)d * CAP + slot] = s;
    } else {
        const int o = atomicAdd(ovf_cnt, 1);
        if (o < OVF_CAP) { ovf[o * 2] = s; ovf[o * 2 + 1] = d; }
    }
}

// ------------------------------------------------------------ pool (v+=) ---
__global__ __launch_bounds__(256) void pool_add_kernel(
    const unsigned short* __restrict__ h, float* __restrict__ v, int cnt)
{
    const int b = blockIdx.x, n = threadIdx.x;
    const unsigned short* hp = &h[(size_t)b * cnt * H_DIM + n];
    float s = 0.f;
    #pragma unroll 8
    for (int r = 0; r < cnt; ++r) s += b2f(hp[(size_t)r * H_DIM]);
    v[b * H_DIM + n] += s;
}

// ----------------------------------------------------- small fp32 GEMM -----
template<bool RELU>
__global__ __launch_bounds__(256) void gemm_small_kernel(
    const float* __restrict__ A, const float* __restrict__ W,
    const float* __restrict__ bias, float* __restrict__ C,
    int M, int N, int K)
{
    constexpr int BM = 32, BN = 64, BK = 32, TM = 2;
    __shared__ __align__(16) float As[BK][BM + 4];
    __shared__ __align__(16) float Bs[BK][BN];
    const int tid = threadIdx.x;
    const int tx = tid & 15;
    const int ty = tid >> 4;
    const int m0 = blockIdx.x * BM;
    const int n0 = blockIdx.y * BN;

    float acc[TM][4] = {};

    for (int kt = 0; kt < K; kt += BK) {
        {
            const int row = tid >> 3, kq = tid & 7;
            const float4 a = *(const float4*)&A[(size_t)(m0 + row) * K + kt + kq * 4];
            As[kq * 4 + 0][row] = a.x;
            As[kq * 4 + 1][row] = a.y;
            As[kq * 4 + 2][row] = a.z;
            As[kq * 4 + 3][row] = a.w;
        }
        #pragma unroll
        for (int i = 0; i < 2; ++i) {
            const int f = tid + i * 256;
            const int row = f >> 4, c4 = f & 15;
            *(float4*)&Bs[row][c4 * 4] =
                *(const float4*)&W[(size_t)(kt + row) * N + n0 + c4 * 4];
        }
        __syncthreads();
        #pragma unroll
        for (int kk = 0; kk < BK; ++kk) {
            const float4 bv = *(const float4*)&Bs[kk][tx * 4];
            #pragma unroll
            for (int im = 0; im < TM; ++im) {
                const float a = As[kk][ty * TM + im];
                acc[im][0] += a * bv.x; acc[im][1] += a * bv.y;
                acc[im][2] += a * bv.z; acc[im][3] += a * bv.w;
            }
        }
        __syncthreads();
    }

    const float4 bb = *(const float4*)&bias[n0 + tx * 4];
    #pragma unroll
    for (int im = 0; im < TM; ++im) {
        const int m = m0 + ty * TM + im;
        float4 r;
        r.x = acc[im][0] + bb.x; r.y = acc[im][1] + bb.y;
        r.z = acc[im][2] + bb.z; r.w = acc[im][3] + bb.w;
        if constexpr (RELU) {
            r.x = fmaxf(r.x, 0.f); r.y = fmaxf(r.y, 0.f);
            r.z = fmaxf(r.z, 0.f); r.w = fmaxf(r.w, 0.f);
        }
        *(float4*)&C[(size_t)m * N + n0 + tx * 4] = r;
    }
}

// ------------------------------------------------------------ conv GEMM ----
// BM=64, BN=256(full width), BK=32, 512 threads.
// GEMM1: Z = relu(Z @ W + b)   (in place; block owns its row stripe)
// GEMM2: Hb(bf16) += Z @ W + b
template<bool GEMM1>
__global__ __launch_bounds__(512) void conv_gemm_kernel(
    float* __restrict__ Z, const float* __restrict__ W,
    const float* __restrict__ bias, unsigned short* __restrict__ Hb)
{
    constexpr int BM = 64, BK = 32, K = H_DIM;
    __shared__ __align__(16) float As[BK][BM + 4];
    __shared__ __align__(16) float Bs[BK][H_DIM];
    const int tid = threadIdx.x;
    const int tx = tid & 63;
    const int ty = tid >> 6;
    const int m0 = blockIdx.x * BM;

    float acc[8][4] = {};

    for (int kt = 0; kt < K; kt += BK) {
        {
            const int row = tid >> 3, kq = tid & 7;
            const float4 a = *(const float4*)&Z[(size_t)(m0 + row) * K + kt + kq * 4];
            As[kq * 4 + 0][row] = a.x;
            As[kq * 4 + 1][row] = a.y;
            As[kq * 4 + 2][row] = a.z;
            As[kq * 4 + 3][row] = a.w;
        }
        #pragma unroll
        for (int i = 0; i < 4; ++i) {
            const int f = tid + i * 512;
            const int row = f >> 6, c4 = f & 63;
            *(float4*)&Bs[row][c4 * 4] =
                *(const float4*)&W[(size_t)(kt + row) * H_DIM + c4 * 4];
        }
        __syncthreads();
        #pragma unroll
        for (int kk = 0; kk < BK; ++kk) {
            const float4 bv = *(const float4*)&Bs[kk][tx * 4];
            float a[8];
            *(float4*)&a[0] = *(const float4*)&As[kk][ty * 8];
            *(float4*)&a[4] = *(const float4*)&As[kk][ty * 8 + 4];
            #pragma unroll
            for (int im = 0; im < 8; ++im) {
                acc[im][0] += a[im] * bv.x; acc[im][1] += a[im] * bv.y;
                acc[im][2] += a[im] * bv.z; acc[im][3] += a[im] * bv.w;
            }
        }
        __syncthreads();
    }

    const float4 bb = *(const float4*)&bias[tx * 4];
    #pragma unroll
    for (int im = 0; im < 8; ++im) {
        const int m = m0 + ty * 8 + im;
        float4 r;
        r.x = acc[im][0] + bb.x; r.y = acc[im][1] + bb.y;
        r.z = acc[im][2] + bb.z; r.w = acc[im][3] + bb.w;
        if constexpr (GEMM1) {
            r.x = fmaxf(r.x, 0.f); r.y = fmaxf(r.y, 0.f);
            r.z = fmaxf(r.z, 0.f); r.w = fmaxf(r.w, 0.f);
            *(float4*)&Z[(size_t)m * H_DIM + tx * 4] = r;
        } else {
            us4* hp = (us4*)&Hb[(size_t)m * H_DIM + tx * 4];
            const us4 old = *hp;
            us4 o;
            o.x = f2b(b2f(old.x) + r.x); o.y = f2b(b2f(old.y) + r.y);
            o.z = f2b(b2f(old.z) + r.z); o.w = f2b(b2f(old.w) + r.w);
            *hp = o;
        }
    }
}

// ------------------------------------------------------------- BN stats ----
__global__ __launch_bounds__(1024) void bn_stats_kernel(
    const float* __restrict__ vtmp, const float* __restrict__ gamma,
    const float* __restrict__ beta, float* __restrict__ scale,
    float* __restrict__ shift)
{
    __shared__ float ssum[4][256];
    __shared__ float ssq[4][256];
    const int n = threadIdx.x & 255;
    const int g = threadIdx.x >> 8;
    float s = 0.f, s2 = 0.f;
    #pragma unroll 8
    for (int r = g; r < BGRAPH; r += 4) {
        const float x = vtmp[(size_t)r * H_DIM + n];
        s += x; s2 += x * x;
    }
    ssum[g][n] = s; ssq[g][n] = s2;
    __syncthreads();
    if (g == 0) {
        s  = ssum[0][n] + ssum[1][n] + ssum[2][n] + ssum[3][n];
        s2 = ssq[0][n]  + ssq[1][n]  + ssq[2][n]  + ssq[3][n];
        const float mean = s * (1.f / BGRAPH);
        const float var  = s2 * (1.f / BGRAPH) - mean * mean;
        const float inv  = rsqrtf(var + 1e-5f);
        const float sc   = gamma[n] * inv;
        scale[n] = sc;
        shift[n] = beta[n] - mean * sc;
    }
}

// -------------------------------------------------------------- BN relu ----
__global__ __launch_bounds__(256) void bn_relu_kernel(
    const float* __restrict__ vtmp, const float* __restrict__ scale,
    const float* __restrict__ shift, float* __restrict__ v)
{
    const int idx = blockIdx.x * 256 + threadIdx.x;
    const int n = idx & 255;
    v[idx] = fmaxf(vtmp[idx] * scale[n] + shift[n], 0.f);
}

// ----------------------------------------------- h(bf16) += v[batch] -------
__global__ __launch_bounds__(256) void h_update_kernel(
    unsigned short* __restrict__ h,
    const float* __restrict__ v, const int* __restrict__ batch)
{
    const size_t i4 = (size_t)blockIdx.x * 256 + threadIdx.x;  // 4-elem group
    const int m = (int)(i4 >> 6);
    const int b = batch[m];
    const us4 hv = ((const us4*)h)[i4];
    const float4 vv = ((const float4*)v)[(size_t)b * 64 + (i4 & 63)];
    us4 o;
    o.x = f2b(b2f(hv.x) + vv.x); o.y = f2b(b2f(hv.y) + vv.y);
    o.z = f2b(b2f(hv.z) + vv.z); o.w = f2b(b2f(hv.w) + vv.w);
    ((us4*)h)[i4] = o;
}

// ----------------------------------------------------------- gather --------
// z[m] = h[m] + sum_{i<deg[m]} h[bucket[m][i]]   (one wave per node)
__global__ __launch_bounds__(256) void gather_kernel(
    const unsigned short* __restrict__ h, const int* __restrict__ deg,
    const int* __restrict__ bucket, float* __restrict__ z)
{
    const int m = blockIdx.x * 4 + (threadIdx.x >> 6);
    const int lane = threadIdx.x & 63;
    int cnt = deg[m]; if (cnt > CAP) cnt = CAP;
    const us4 hv = *(const us4*)&h[(size_t)m * H_DIM + lane * 4];
    float4 acc = { b2f(hv.x), b2f(hv.y), b2f(hv.z), b2f(hv.w) };
    const int* bp = &bucket[(size_t)m * CAP];
    for (int i = 0; i < cnt; ++i) {
        const int s = bp[i];
        const us4 sv = *(const us4*)&h[(size_t)s * H_DIM + lane * 4];
        acc.x += b2f(sv.x); acc.y += b2f(sv.y);
        acc.z += b2f(sv.z); acc.w += b2f(sv.w);
    }
    *(float4*)&z[(size_t)m * H_DIM + lane * 4] = acc;
}

// --------------------------------------------------- overflow (rare) -------
__global__ __launch_bounds__(256) void overflow_kernel(
    const int* __restrict__ ovf, const int* __restrict__ ovf_cnt,
    const unsigned short* __restrict__ h, float* __restrict__ z)
{
    int n = *ovf_cnt; if (n > OVF_CAP) n = OVF_CAP;
    const int w = (blockIdx.x * 256 + threadIdx.x) >> 6;   // 64 waves total
    const int lane = threadIdx.x & 63;
    for (int i = w; i < n; i += 64) {
        const int s = ovf[i * 2], d = ovf[i * 2 + 1];
        const us4 sv = *(const us4*)&h[(size_t)s * H_DIM + lane * 4];
        float* zp = &z[(size_t)d * H_DIM + lane * 4];
        atomicAdd(zp + 0, b2f(sv.x));
        atomicAdd(zp + 1, b2f(sv.y));
        atomicAdd(zp + 2, b2f(sv.z));
        atomicAdd(zp + 3, b2f(sv.w));
    }
}

// ----------------------------------------------------- final mean pools ----
__global__ __launch_bounds__(256) void pool_final_kernel(
    const unsigned short* __restrict__ lig_h,
    const unsigned short* __restrict__ prot_h, float* __restrict__ comb)
{
    const int b = blockIdx.x, n = threadIdx.x;
    float s = 0.f;
    #pragma unroll 8
    for (int r = 0; r < 64; ++r) s += b2f(lig_h[(size_t)(b * 64 + r) * H_DIM + n]);
    comb[(size_t)b * 512 + n] = s * (1.f / 64.f);
    float s2 = 0.f;
    #pragma unroll 8
    for (int r = 0; r < 128; ++r) s2 += b2f(prot_h[(size_t)(b * 128 + r) * H_DIM + n]);
    comb[(size_t)b * 512 + 256 + n] = s2 * (1.f / 128.f);
}

// ------------------------------------------------------------ final dot ----
__global__ __launch_bounds__(256) void pred_final_kernel(
    const float* __restrict__ hidden, const float* __restrict__ W2,
    const float* __restrict__ b2, float* __restrict__ out)
{
    const int b = blockIdx.x, t = threadIdx.x;
    float p = hidden[(size_t)b * H_DIM + t] * W2[t];
    #pragma unroll
    for (int off = 32; off >= 1; off >>= 1) p += __shfl_down(p, off);
    __shared__ float red[4];
    if ((t & 63) == 0) red[t >> 6] = p;
    __syncthreads();
    if (t == 0) out[b] = red[0] + red[1] + red[2] + red[3] + b2[0];
}

// ===========================================================================
extern "C" void kernel_launch(void* const* d_in, const int* in_sizes, int n_in,
                              void* d_out, int out_size, void* d_ws, size_t ws_size,
                              hipStream_t stream)
{
    const int NL = 65536, NP = 131072, EL = 262144, EP = 524288;
    const int B = BGRAPH, H = H_DIM;

    const float* lig_x        = (const float*)d_in[0];
    const float* prot_x       = (const float*)d_in[1];
    const float* lig_embed_W  = (const float*)d_in[2];
    const float* lig_embed_b  = (const float*)d_in[3];
    const float* prot_embed_W = (const float*)d_in[4];
    const float* prot_embed_b = (const float*)d_in[5];
    const float* lig_virtual0 = (const float*)d_in[6];
    const float* prot_virtual0= (const float*)d_in[7];
    const float* lig_conv_W1  = (const float*)d_in[8];
    const float* lig_conv_b1  = (const float*)d_in[9];
    const float* lig_conv_W2  = (const float*)d_in[10];
    const float* lig_conv_b2  = (const float*)d_in[11];
    const float* lig_vmlp_W   = (const float*)d_in[12];
    const float* lig_vmlp_b   = (const float*)d_in[13];
    const float* lig_vmlp_g   = (const float*)d_in[14];
    const float* lig_vmlp_be  = (const float*)d_in[15];
    const float* prot_conv_W1 = (const float*)d_in[16];
    const float* prot_conv_b1 = (const float*)d_in[17];
    const float* prot_conv_W2 = (const float*)d_in[18];
    const float* prot_conv_b2 = (const float*)d_in[19];
    const float* prot_vmlp_W  = (const float*)d_in[20];
    const float* prot_vmlp_b  = (const float*)d_in[21];
    const float* prot_vmlp_g  = (const float*)d_in[22];
    const float* prot_vmlp_be = (const float*)d_in[23];
    const float* pred_W1      = (const float*)d_in[24];
    const float* pred_b1      = (const float*)d_in[25];
    const float* pred_W2      = (const float*)d_in[26];
    const float* pred_b2      = (const float*)d_in[27];
    const int* lig_batch      = (const int*)d_in[28];
    const int* prot_batch     = (const int*)d_in[29];
    const int* lig_ei         = (const int*)d_in[30];
    const int* prot_ei        = (const int*)d_in[31];

    // ---- workspace layout (~255 MB) ----
    float* ws = (float*)d_ws;
    float* zbuf   = ws;                        // NP*H f32 (shared lig/prot)
    float* lig_v  = zbuf   + (size_t)NP * H;   // B*H
    float* prot_v = lig_v  + (size_t)B * H;    // B*H
    float* vtmp   = prot_v + (size_t)B * H;    // B*H
    float* scale  = vtmp   + (size_t)B * H;    // H
    float* shift  = scale  + H;                // H
    float* comb   = shift  + H;                // B*2H
    float* hidden = comb   + (size_t)B * 2 * H;// B*H
    unsigned short* lig_h  = (unsigned short*)(hidden + (size_t)B * H); // NL*H bf16
    unsigned short* prot_h = lig_h + (size_t)NL * H;                    // NP*H bf16
    int* deg_lig    = (int*)(prot_h + (size_t)NP * H); // NL
    int* deg_prot   = deg_lig  + NL;                   // NP
    int* bkt_lig    = deg_prot + NP;                   // NL*CAP
    int* bkt_prot   = bkt_lig  + (size_t)NL * CAP;     // NP*CAP
    int* ovf_lig    = bkt_prot + (size_t)NP * CAP;     // OVF_CAP*2
    int* ovf_prot   = ovf_lig  + OVF_CAP * 2;          // OVF_CAP*2
    int* ovf_cnts   = ovf_prot + OVF_CAP * 2;          // 2 (+pad)

    // ---- zero degree/overflow counters, then build buckets (once/call) ----
    hipMemsetAsync(deg_lig, 0, (size_t)(NL + NP) * sizeof(int), stream);
    hipMemsetAsync(ovf_cnts, 0, 2 * sizeof(int), stream);
    bucket_build_kernel<<<EL / 256, 256, 0, stream>>>(
        lig_ei, lig_ei + EL, EL, deg_lig, bkt_lig, ovf_lig, ovf_cnts);
    bucket_build_kernel<<<EP / 256, 256, 0, stream>>>(
        prot_ei, prot_ei + EP, EP, deg_prot, bkt_prot, ovf_prot, ovf_cnts + 1);

    // ---- embeddings ----
    embed_kernel<<<NL / 8, 256, 0, stream>>>(lig_x, lig_embed_W, lig_embed_b, lig_h, 26);
    embed_kernel<<<NP / 8, 256, 0, stream>>>(prot_x, prot_embed_W, prot_embed_b, prot_h, 20);
    init_v_kernel<<<B, 256, 0, stream>>>(lig_virtual0, prot_virtual0, lig_v, prot_v);

    auto layer = [&](unsigned short* h, int Nn, int cnt, float* v,
                     const float* vW, const float* vb, const float* vg, const float* vbe,
                     const float* W1, const float* b1, const float* W2, const float* b2,
                     const int* batch, const int* deg, const int* bkt,
                     const int* ovf, const int* ovf_cnt) {
        pool_add_kernel<<<B, 256, 0, stream>>>(h, v, cnt);
        gemm_small_kernel<false><<<dim3(B / 32, 4), 256, 0, stream>>>(
            v, vW, vb, vtmp, B, H, H);
        bn_stats_kernel<<<1, 1024, 0, stream>>>(vtmp, vg, vbe, scale, shift);
        bn_relu_kernel<<<B, 256, 0, stream>>>(vtmp, scale, shift, v);
        h_update_kernel<<<Nn / 4, 256, 0, stream>>>(h, v, batch);
        gather_kernel<<<Nn / 4, 256, 0, stream>>>(h, deg, bkt, zbuf);
        overflow_kernel<<<16, 256, 0, stream>>>(ovf, ovf_cnt, h, zbuf);
        conv_gemm_kernel<true><<<Nn / 64, 512, 0, stream>>>(zbuf, W1, b1, nullptr);
        conv_gemm_kernel<false><<<Nn / 64, 512, 0, stream>>>(zbuf, W2, b2, h);
    };

    for (int i = 0; i < NLAYER; ++i) {
        const size_t wo = (size_t)i * H * H;
        const size_t bo = (size_t)i * H;
        layer(lig_h, NL, 64, lig_v,
              lig_vmlp_W + wo, lig_vmlp_b + bo, lig_vmlp_g + bo, lig_vmlp_be + bo,
              lig_conv_W1 + wo, lig_conv_b1 + bo, lig_conv_W2 + wo, lig_conv_b2 + bo,
              lig_batch, deg_lig, bkt_lig, ovf_lig, ovf_cnts);
        layer(prot_h, NP, 128, prot_v,
              prot_vmlp_W + wo, prot_vmlp_b + bo, prot_vmlp_g + bo, prot_vmlp_be + bo,
              prot_conv_W1 + wo, prot_conv_b1 + bo, prot_conv_W2 + wo, prot_conv_b2 + bo,
              prot_batch, deg_prot, bkt_prot, ovf_prot, ovf_cnts + 1);
    }

    // ---- readout ----
    pool_final_kernel<<<B, 256, 0, stream>>>(lig_h, prot_h, comb);
    gemm_small_kernel<true><<<dim3(B / 32, 4), 256, 0, stream>>>(
        comb, pred_W1, pred_b1, hidden, B, H, 2 * H);
    pred_final_kernel<<<B, 256, 0, stream>>>(hidden, pred_W2, pred_b2, (float*)d_out);
}

// Round 4
// 2162.645 us; speedup vs baseline: 7.9379x; 2.1426x over previous
//
#include <hip/hip_runtime.h>

#define H_DIM 256
#define NLAYER 5
#define BGRAPH 1024
#define CAP 16
#define OVF_CAP 4096

typedef __attribute__((ext_vector_type(8))) short short8;
typedef __attribute__((ext_vector_type(4))) float f32x4;
typedef const __attribute__((address_space(1))) unsigned int* gas_ptr;
typedef __attribute__((address_space(3))) unsigned int* las_ptr;

// ---- bf16 helpers (storage-only; math fp32 / MFMA-fp32-accum) ----
struct __align__(8) us4 { unsigned short x, y, z, w; };

__device__ __forceinline__ float b2f(unsigned short u) {
    union { float f; unsigned v; } c; c.v = ((unsigned)u) << 16; return c.f;
}
__device__ __forceinline__ unsigned short f2b(float f) {
    union { float f; unsigned v; } c; c.f = f;
    return (unsigned short)((c.v + 0x7fffu + ((c.v >> 16) & 1u)) >> 16);
}

// ---------------------------------------------------------------- embed ----
__global__ __launch_bounds__(256) void embed_kernel(
    const float* __restrict__ x, const float* __restrict__ W,
    const float* __restrict__ b, unsigned short* __restrict__ h, int K)
{
    __shared__ float xs[256];            // 8 rows * K (K <= 32)
    const int m0 = blockIdx.x * 8;
    const int tid = threadIdx.x;
    if (tid < 8 * K) xs[tid] = x[(size_t)m0 * K + tid];
    __syncthreads();
    const int n = tid;
    float acc[8] = {0.f,0.f,0.f,0.f,0.f,0.f,0.f,0.f};
    for (int k = 0; k < K; ++k) {
        const float w = W[k * H_DIM + n];
        #pragma unroll
        for (int r = 0; r < 8; ++r) acc[r] += xs[r * K + k] * w;
    }
    const float bb = b[n];
    #pragma unroll
    for (int r = 0; r < 8; ++r)
        h[(size_t)(m0 + r) * H_DIM + n] = f2b(acc[r] + bb);
}

// ---------------------------------------------------------------- init v ---
__global__ __launch_bounds__(256) void init_v_kernel(
    const float* __restrict__ lig0, const float* __restrict__ prot0,
    float* __restrict__ lig_v, float* __restrict__ prot_v)
{
    const int b = blockIdx.x, n = threadIdx.x;
    lig_v[b * H_DIM + n]  = lig0[n];
    prot_v[b * H_DIM + n] = prot0[n];
}

// ------------------------------------------------- weight prep (W->Wt bf16)
// Wt[l][n][k] = bf16(W[l][k][n]);  64x64 tiles via LDS
__global__ __launch_bounds__(256) void wprep_kernel(
    const float* __restrict__ W, unsigned short* __restrict__ Wt)
{
    __shared__ float t[64][65];
    const int l = blockIdx.z;
    const int k0 = blockIdx.x * 64, n0 = blockIdx.y * 64;
    const int tid = threadIdx.x;
    const int c = tid & 63, r4 = tid >> 6;
    const float* Wl = W + (size_t)l * 65536;
    unsigned short* Wtl = Wt + (size_t)l * 65536;
    #pragma unroll
    for (int i = 0; i < 16; ++i) {
        const int r = i * 4 + r4;
        t[r][c] = Wl[(size_t)(k0 + r) * 256 + n0 + c];
    }
    __syncthreads();
    #pragma unroll
    for (int i = 0; i < 16; ++i) {
        const int n = i * 4 + r4;
        Wtl[(size_t)(n0 + n) * 256 + k0 + c] = f2b(t[c][n]);
    }
}

// ------------------------------------------------------- bucket build ------
__global__ __launch_bounds__(256) void bucket_build_kernel(
    const int* __restrict__ src, const int* __restrict__ dst, int E,
    int* __restrict__ deg, int* __restrict__ bucket,
    int* __restrict__ ovf, int* __restrict__ ovf_cnt)
{
    const int e = blockIdx.x * 256 + threadIdx.x;
    if (e >= E) return;
    const int d = dst[e], s = src[e];
    const int slot = atomicAdd(&deg[d], 1);
    if (slot < CAP) {
        bucket[(size_t)d * CAP + slot] = s;
    } else {
        const int o = atomicAdd(ovf_cnt, 1);
        if (o < OVF_CAP) { ovf[o * 2] = s; ovf[o * 2 + 1] = d; }
    }
}

// ------------------------------------------------------------ pool (v+=) ---
__global__ __launch_bounds__(256) void pool_add_kernel(
    const unsigned short* __restrict__ h, float* __restrict__ v, int cnt)
{
    const int b = blockIdx.x, n = threadIdx.x;
    const unsigned short* hp = &h[(size_t)b * cnt * H_DIM + n];
    float s = 0.f;
    #pragma unroll 8
    for (int r = 0; r < cnt; ++r) s += b2f(hp[(size_t)r * H_DIM]);
    v[b * H_DIM + n] += s;
}

// ----------------------------------------------------- small fp32 GEMM -----
template<bool RELU>
__global__ __launch_bounds__(256) void gemm_small_kernel(
    const float* __restrict__ A, const float* __restrict__ W,
    const float* __restrict__ bias, float* __restrict__ C,
    int M, int N, int K)
{
    constexpr int BM = 32, BN = 64, BK = 32, TM = 2;
    __shared__ __align__(16) float As[BK][BM + 4];
    __shared__ __align__(16) float Bs[BK][BN];
    const int tid = threadIdx.x;
    const int tx = tid & 15;
    const int ty = tid >> 4;
    const int m0 = blockIdx.x * BM;
    const int n0 = blockIdx.y * BN;

    float acc[TM][4] = {};

    for (int kt = 0; kt < K; kt += BK) {
        {
            const int row = tid >> 3, kq = tid & 7;
            const float4 a = *(const float4*)&A[(size_t)(m0 + row) * K + kt + kq * 4];
            As[kq * 4 + 0][row] = a.x;
            As[kq * 4 + 1][row] = a.y;
            As[kq * 4 + 2][row] = a.z;
            As[kq * 4 + 3][row] = a.w;
        }
        #pragma unroll
        for (int i = 0; i < 2; ++i) {
            const int f = tid + i * 256;
            const int row = f >> 4, c4 = f & 15;
            *(float4*)&Bs[row][c4 * 4] =
                *(const float4*)&W[(size_t)(kt + row) * N + n0 + c4 * 4];
        }
        __syncthreads();
        #pragma unroll
        for (int kk = 0; kk < BK; ++kk) {
            const float4 bv = *(const float4*)&Bs[kk][tx * 4];
            #pragma unroll
            for (int im = 0; im < TM; ++im) {
                const float a = As[kk][ty * TM + im];
                acc[im][0] += a * bv.x; acc[im][1] += a * bv.y;
                acc[im][2] += a * bv.z; acc[im][3] += a * bv.w;
            }
        }
        __syncthreads();
    }

    const float4 bb = *(const float4*)&bias[n0 + tx * 4];
    #pragma unroll
    for (int im = 0; im < TM; ++im) {
        const int m = m0 + ty * TM + im;
        float4 r;
        r.x = acc[im][0] + bb.x; r.y = acc[im][1] + bb.y;
        r.z = acc[im][2] + bb.z; r.w = acc[im][3] + bb.w;
        if constexpr (RELU) {
            r.x = fmaxf(r.x, 0.f); r.y = fmaxf(r.y, 0.f);
            r.z = fmaxf(r.z, 0.f); r.w = fmaxf(r.w, 0.f);
        }
        *(float4*)&C[(size_t)m * N + n0 + tx * 4] = r;
    }
}

// ------------------------------------------------------ conv MFMA GEMM -----
// A[M,256] bf16 row-major, Bt[256,256] bf16 (Bt[n][k] = W[k][n]).
// BM=128, BN=256 (full width), BK=32, 512 threads = 8 waves (2x4 of 64x64).
// GEMM1: Z = relu(Z @ W + b)  in place (block owns its 128-row stripe)
// GEMM2: H(bf16) += Z @ W + b
template<bool GEMM1>
__global__ __launch_bounds__(512) void conv_mfma_kernel(
    unsigned short* __restrict__ A, const unsigned short* __restrict__ Bt,
    const float* __restrict__ bias, unsigned short* __restrict__ Out)
{
    constexpr int K = 256, BM = 128, BK = 32;
    __shared__ unsigned short As[BM][BK];     // 8 KB, linear
    __shared__ unsigned short Bs[H_DIM][BK];  // 16 KB, linear
    const int tid  = threadIdx.x;
    const int lane = tid & 63;
    const int wid  = tid >> 6;      // 0..7
    const int wr   = wid >> 2;      // row block (64)
    const int wc   = wid & 3;       // col block (64)
    const int m0   = blockIdx.x * BM;

    f32x4 acc[4][4];
    #pragma unroll
    for (int i = 0; i < 4; ++i)
        #pragma unroll
        for (int j = 0; j < 4; ++j) acc[i][j] = (f32x4){0.f, 0.f, 0.f, 0.f};

    // staging coordinates (16B chunks)
    const int arow = tid >> 2, akq = tid & 3;            // A: 512 chunks
    const unsigned short* asrc0 = &A[(size_t)(m0 + arow) * K + akq * 8];
    const int albase = (tid & ~63) * 16;                 // wave-uniform byte
    unsigned short* lAs = &As[0][0];
    unsigned short* lBs = &Bs[0][0];

    for (int kt = 0; kt < K; kt += BK) {
        // ---- stage A (1 chunk/thread) + B (2 chunks/thread) ----
        __builtin_amdgcn_global_load_lds(
            (gas_ptr)(asrc0 + kt), (las_ptr)((char*)lAs + albase), 16, 0, 0);
        #pragma unroll
        for (int i = 0; i < 2; ++i) {
            const int c = tid + i * 512;
            const int n = c >> 2, kq = c & 3;
            __builtin_amdgcn_global_load_lds(
                (gas_ptr)&Bt[(size_t)n * K + kt + kq * 8],
                (las_ptr)((char*)lBs + albase + i * 512 * 16), 16, 0, 0);
        }
        __syncthreads();   // drains vmcnt before LDS reads

        // ---- fragments + 16 MFMA ----
        short8 av[4], bv[4];
        #pragma unroll
        for (int mi = 0; mi < 4; ++mi)
            av[mi] = *(const short8*)&As[wr * 64 + mi * 16 + (lane & 15)][(lane >> 4) * 8];
        #pragma unroll
        for (int ni = 0; ni < 4; ++ni)
            bv[ni] = *(const short8*)&Bs[wc * 64 + ni * 16 + (lane & 15)][(lane >> 4) * 8];
        #pragma unroll
        for (int mi = 0; mi < 4; ++mi)
            #pragma unroll
            for (int ni = 0; ni < 4; ++ni)
                acc[mi][ni] = __builtin_amdgcn_mfma_f32_16x16x32_bf16(
                    av[mi], bv[ni], acc[mi][ni], 0, 0, 0);
        __syncthreads();   // protect LDS before next stage
    }

    // ---- epilogue ----
    #pragma unroll
    for (int ni = 0; ni < 4; ++ni) {
        const int col = wc * 64 + ni * 16 + (lane & 15);
        const float bb = bias[col];
        #pragma unroll
        for (int mi = 0; mi < 4; ++mi) {
            #pragma unroll
            for (int j = 0; j < 4; ++j) {
                const int row = m0 + wr * 64 + mi * 16 + ((lane >> 4) << 2) + j;
                const float val = acc[mi][ni][j] + bb;
                if constexpr (GEMM1) {
                    A[(size_t)row * H_DIM + col] = f2b(fmaxf(val, 0.f));
                } else {
                    unsigned short* op = &Out[(size_t)row * H_DIM + col];
                    *op = f2b(b2f(*op) + val);
                }
            }
        }
    }
}

// ------------------------------------------------------------- BN stats ----
__global__ __launch_bounds__(1024) void bn_stats_kernel(
    const float* __restrict__ vtmp, const float* __restrict__ gamma,
    const float* __restrict__ beta, float* __restrict__ scale,
    float* __restrict__ shift)
{
    __shared__ float ssum[4][256];
    __shared__ float ssq[4][256];
    const int n = threadIdx.x & 255;
    const int g = threadIdx.x >> 8;
    float s = 0.f, s2 = 0.f;
    #pragma unroll 8
    for (int r = g; r < BGRAPH; r += 4) {
        const float x = vtmp[(size_t)r * H_DIM + n];
        s += x; s2 += x * x;
    }
    ssum[g][n] = s; ssq[g][n] = s2;
    __syncthreads();
    if (g == 0) {
        s  = ssum[0][n] + ssum[1][n] + ssum[2][n] + ssum[3][n];
        s2 = ssq[0][n]  + ssq[1][n]  + ssq[2][n]  + ssq[3][n];
        const float mean = s * (1.f / BGRAPH);
        const float var  = s2 * (1.f / BGRAPH) - mean * mean;
        const float inv  = rsqrtf(var + 1e-5f);
        const float sc   = gamma[n] * inv;
        scale[n] = sc;
        shift[n] = beta[n] - mean * sc;
    }
}

// -------------------------------------------------------------- BN relu ----
__global__ __launch_bounds__(256) void bn_relu_kernel(
    const float* __restrict__ vtmp, const float* __restrict__ scale,
    const float* __restrict__ shift, float* __restrict__ v)
{
    const int idx = blockIdx.x * 256 + threadIdx.x;
    const int n = idx & 255;
    v[idx] = fmaxf(vtmp[idx] * scale[n] + shift[n], 0.f);
}

// ----------------------------------------------- h(bf16) += v[batch] -------
__global__ __launch_bounds__(256) void h_update_kernel(
    unsigned short* __restrict__ h,
    const float* __restrict__ v, const int* __restrict__ batch)
{
    const size_t i4 = (size_t)blockIdx.x * 256 + threadIdx.x;
    const int m = (int)(i4 >> 6);
    const int b = batch[m];
    const us4 hv = ((const us4*)h)[i4];
    const float4 vv = ((const float4*)v)[(size_t)b * 64 + (i4 & 63)];
    us4 o;
    o.x = f2b(b2f(hv.x) + vv.x); o.y = f2b(b2f(hv.y) + vv.y);
    o.z = f2b(b2f(hv.z) + vv.z); o.w = f2b(b2f(hv.w) + vv.w);
    ((us4*)h)[i4] = o;
}

// ----------------------------------------------------------- gather --------
// z[m] = bf16( h[m] + sum_{i<deg[m]} h[bucket[m][i]] )   (one wave per node)
__global__ __launch_bounds__(256) void gather_kernel(
    const unsigned short* __restrict__ h, const int* __restrict__ deg,
    const int* __restrict__ bucket, unsigned short* __restrict__ z)
{
    const int m = blockIdx.x * 4 + (threadIdx.x >> 6);
    const int lane = threadIdx.x & 63;
    int cnt = deg[m]; if (cnt > CAP) cnt = CAP;
    const us4 hv = *(const us4*)&h[(size_t)m * H_DIM + lane * 4];
    float4 acc = { b2f(hv.x), b2f(hv.y), b2f(hv.z), b2f(hv.w) };
    const int* bp = &bucket[(size_t)m * CAP];
    for (int i = 0; i < cnt; ++i) {
        const int s = bp[i];
        const us4 sv = *(const us4*)&h[(size_t)s * H_DIM + lane * 4];
        acc.x += b2f(sv.x); acc.y += b2f(sv.y);
        acc.z += b2f(sv.z); acc.w += b2f(sv.w);
    }
    us4 o = { f2b(acc.x), f2b(acc.y), f2b(acc.z), f2b(acc.w) };
    *(us4*)&z[(size_t)m * H_DIM + lane * 4] = o;
}

// --------------------------------------------- overflow (rare, serial) -----
// single wave processes overflow edges sequentially -> no atomics needed
__global__ __launch_bounds__(64) void overflow_kernel(
    const int* __restrict__ ovf, const int* __restrict__ ovf_cnt,
    const unsigned short* __restrict__ h, unsigned short* __restrict__ z)
{
    int n = *ovf_cnt; if (n > OVF_CAP) n = OVF_CAP;
    const int lane = threadIdx.x;
    for (int i = 0; i < n; ++i) {
        const int s = ovf[i * 2], d = ovf[i * 2 + 1];
        const us4 sv = *(const us4*)&h[(size_t)s * H_DIM + lane * 4];
        us4* zp = (us4*)&z[(size_t)d * H_DIM + lane * 4];
        us4 zv = *zp;
        zv.x = f2b(b2f(zv.x) + b2f(sv.x)); zv.y = f2b(b2f(zv.y) + b2f(sv.y));
        zv.z = f2b(b2f(zv.z) + b2f(sv.z)); zv.w = f2b(b2f(zv.w) + b2f(sv.w));
        *zp = zv;
        __builtin_amdgcn_s_waitcnt(0);  // keep sequential per iteration
    }
}

// ----------------------------------------------------- final mean pools ----
__global__ __launch_bounds__(256) void pool_final_kernel(
    const unsigned short* __restrict__ lig_h,
    const unsigned short* __restrict__ prot_h, float* __restrict__ comb)
{
    const int b = blockIdx.x, n = threadIdx.x;
    float s = 0.f;
    #pragma unroll 8
    for (int r = 0; r < 64; ++r) s += b2f(lig_h[(size_t)(b * 64 + r) * H_DIM + n]);
    comb[(size_t)b * 512 + n] = s * (1.f / 64.f);
    float s2 = 0.f;
    #pragma unroll 8
    for (int r = 0; r < 128; ++r) s2 += b2f(prot_h[(size_t)(b * 128 + r) * H_DIM + n]);
    comb[(size_t)b * 512 + 256 + n] = s2 * (1.f / 128.f);
}

// ------------------------------------------------------------ final dot ----
__global__ __launch_bounds__(256) void pred_final_kernel(
    const float* __restrict__ hidden, const float* __restrict__ W2,
    const float* __restrict__ b2, float* __restrict__ out)
{
    const int b = blockIdx.x, t = threadIdx.x;
    float p = hidden[(size_t)b * H_DIM + t] * W2[t];
    #pragma unroll
    for (int off = 32; off >= 1; off >>= 1) p += __shfl_down(p, off);
    __shared__ float red[4];
    if ((t & 63) == 0) red[t >> 6] = p;
    __syncthreads();
    if (t == 0) out[b] = red[0] + red[1] + red[2] + red[3] + b2[0];
}

// ===========================================================================
extern "C" void kernel_launch(void* const* d_in, const int* in_sizes, int n_in,
                              void* d_out, int out_size, void* d_ws, size_t ws_size,
                              hipStream_t stream)
{
    const int NL = 65536, NP = 131072, EL = 262144, EP = 524288;
    const int B = BGRAPH, H = H_DIM;

    const float* lig_x        = (const float*)d_in[0];
    const float* prot_x       = (const float*)d_in[1];
    const float* lig_embed_W  = (const float*)d_in[2];
    const float* lig_embed_b  = (const float*)d_in[3];
    const float* prot_embed_W = (const float*)d_in[4];
    const float* prot_embed_b = (const float*)d_in[5];
    const float* lig_virtual0 = (const float*)d_in[6];
    const float* prot_virtual0= (const float*)d_in[7];
    const float* lig_conv_W1  = (const float*)d_in[8];
    const float* lig_conv_b1  = (const float*)d_in[9];
    const float* lig_conv_W2  = (const float*)d_in[10];
    const float* lig_conv_b2  = (const float*)d_in[11];
    const float* lig_vmlp_W   = (const float*)d_in[12];
    const float* lig_vmlp_b   = (const float*)d_in[13];
    const float* lig_vmlp_g   = (const float*)d_in[14];
    const float* lig_vmlp_be  = (const float*)d_in[15];
    const float* prot_conv_W1 = (const float*)d_in[16];
    const float* prot_conv_b1 = (const float*)d_in[17];
    const float* prot_conv_W2 = (const float*)d_in[18];
    const float* prot_conv_b2 = (const float*)d_in[19];
    const float* prot_vmlp_W  = (const float*)d_in[20];
    const float* prot_vmlp_b  = (const float*)d_in[21];
    const float* prot_vmlp_g  = (const float*)d_in[22];
    const float* prot_vmlp_be = (const float*)d_in[23];
    const float* pred_W1      = (const float*)d_in[24];
    const float* pred_b1      = (const float*)d_in[25];
    const float* pred_W2      = (const float*)d_in[26];
    const float* pred_b2      = (const float*)d_in[27];
    const int* lig_batch      = (const int*)d_in[28];
    const int* prot_batch     = (const int*)d_in[29];
    const int* lig_ei         = (const int*)d_in[30];
    const int* prot_ei        = (const int*)d_in[31];

    // ---- workspace layout (~191 MB) ----
    float* ws = (float*)d_ws;
    float* lig_v  = ws;                        // B*H
    float* prot_v = lig_v  + (size_t)B * H;    // B*H
    float* vtmp   = prot_v + (size_t)B * H;    // B*H
    float* scale  = vtmp   + (size_t)B * H;    // H
    float* shift  = scale  + H;                // H
    float* comb   = shift  + H;                // B*2H
    float* hidden = comb   + (size_t)B * 2 * H;// B*H
    unsigned short* zbuf   = (unsigned short*)(hidden + (size_t)B * H); // NP*H bf16
    unsigned short* lig_h  = zbuf  + (size_t)NP * H;                    // NL*H bf16
    unsigned short* prot_h = lig_h + (size_t)NL * H;                    // NP*H bf16
    unsigned short* wt_lw1 = prot_h + (size_t)NP * H;   // 5*H*H bf16 each
    unsigned short* wt_lw2 = wt_lw1 + (size_t)NLAYER * H * H;
    unsigned short* wt_pw1 = wt_lw2 + (size_t)NLAYER * H * H;
    unsigned short* wt_pw2 = wt_pw1 + (size_t)NLAYER * H * H;
    int* deg_lig  = (int*)(wt_pw2 + (size_t)NLAYER * H * H); // NL
    int* deg_prot = deg_lig  + NL;                   // NP
    int* bkt_lig  = deg_prot + NP;                   // NL*CAP
    int* bkt_prot = bkt_lig  + (size_t)NL * CAP;     // NP*CAP
    int* ovf_lig  = bkt_prot + (size_t)NP * CAP;     // OVF_CAP*2
    int* ovf_prot = ovf_lig  + OVF_CAP * 2;          // OVF_CAP*2
    int* ovf_cnts = ovf_prot + OVF_CAP * 2;          // 2

    // ---- one-time-per-call prep ----
    hipMemsetAsync(deg_lig, 0, (size_t)(NL + NP) * sizeof(int), stream);
    hipMemsetAsync(ovf_cnts, 0, 2 * sizeof(int), stream);
    bucket_build_kernel<<<EL / 256, 256, 0, stream>>>(
        lig_ei, lig_ei + EL, EL, deg_lig, bkt_lig, ovf_lig, ovf_cnts);
    bucket_build_kernel<<<EP / 256, 256, 0, stream>>>(
        prot_ei, prot_ei + EP, EP, deg_prot, bkt_prot, ovf_prot, ovf_cnts + 1);
    wprep_kernel<<<dim3(4, 4, NLAYER), 256, 0, stream>>>(lig_conv_W1, wt_lw1);
    wprep_kernel<<<dim3(4, 4, NLAYER), 256, 0, stream>>>(lig_conv_W2, wt_lw2);
    wprep_kernel<<<dim3(4, 4, NLAYER), 256, 0, stream>>>(prot_conv_W1, wt_pw1);
    wprep_kernel<<<dim3(4, 4, NLAYER), 256, 0, stream>>>(prot_conv_W2, wt_pw2);

    // ---- embeddings ----
    embed_kernel<<<NL / 8, 256, 0, stream>>>(lig_x, lig_embed_W, lig_embed_b, lig_h, 26);
    embed_kernel<<<NP / 8, 256, 0, stream>>>(prot_x, prot_embed_W, prot_embed_b, prot_h, 20);
    init_v_kernel<<<B, 256, 0, stream>>>(lig_virtual0, prot_virtual0, lig_v, prot_v);

    auto layer = [&](unsigned short* h, int Nn, int cnt, float* v,
                     const float* vW, const float* vb, const float* vg, const float* vbe,
                     const unsigned short* Wt1, const float* b1,
                     const unsigned short* Wt2, const float* b2,
                     const int* batch, const int* deg, const int* bkt,
                     const int* ovf, const int* ovf_cnt) {
        pool_add_kernel<<<B, 256, 0, stream>>>(h, v, cnt);
        gemm_small_kernel<false><<<dim3(B / 32, 4), 256, 0, stream>>>(
            v, vW, vb, vtmp, B, H, H);
        bn_stats_kernel<<<1, 1024, 0, stream>>>(vtmp, vg, vbe, scale, shift);
        bn_relu_kernel<<<B, 256, 0, stream>>>(vtmp, scale, shift, v);
        h_update_kernel<<<Nn / 4, 256, 0, stream>>>(h, v, batch);
        gather_kernel<<<Nn / 4, 256, 0, stream>>>(h, deg, bkt, zbuf);
        overflow_kernel<<<1, 64, 0, stream>>>(ovf, ovf_cnt, h, zbuf);
        conv_mfma_kernel<true><<<Nn / 128, 512, 0, stream>>>(zbuf, Wt1, b1, nullptr);
        conv_mfma_kernel<false><<<Nn / 128, 512, 0, stream>>>(zbuf, Wt2, b2, h);
    };

    for (int i = 0; i < NLAYER; ++i) {
        const size_t wo = (size_t)i * H * H;
        const size_t bo = (size_t)i * H;
        layer(lig_h, NL, 64, lig_v,
              lig_vmlp_W + wo, lig_vmlp_b + bo, lig_vmlp_g + bo, lig_vmlp_be + bo,
              wt_lw1 + wo, lig_conv_b1 + bo, wt_lw2 + wo, lig_conv_b2 + bo,
              lig_batch, deg_lig, bkt_lig, ovf_lig, ovf_cnts);
        layer(prot_h, NP, 128, prot_v,
              prot_vmlp_W + wo, prot_vmlp_b + bo, prot_vmlp_g + bo, prot_vmlp_be + bo,
              wt_pw1 + wo, prot_conv_b1 + bo, wt_pw2 + wo, prot_conv_b2 + bo,
              prot_batch, deg_prot, bkt_prot, ovf_prot, ovf_cnts + 1);
    }

    // ---- readout ----
    pool_final_kernel<<<B, 256, 0, stream>>>(lig_h, prot_h, comb);
    gemm_small_kernel<true><<<dim3(B / 32, 4), 256, 0, stream>>>(
        comb, pred_W1, pred_b1, hidden, B, H, 2 * H);
    pred_final_kernel<<<B, 256, 0, stream>>>(hidden, pred_W2, pred_b2, (float*)d_out);
}

// Round 5
// 1799.295 us; speedup vs baseline: 9.5409x; 1.2019x over previous
//
#include <hip/hip_runtime.h>

#define H_DIM 256
#define NLAYER 5
#define BGRAPH 1024
#define CAP 16
#define OVF_CAP 4096

typedef __attribute__((ext_vector_type(8))) short short8;
typedef __attribute__((ext_vector_type(4))) float f32x4;
typedef const __attribute__((address_space(1))) unsigned int* gas_ptr;
typedef __attribute__((address_space(3))) unsigned int* las_ptr;

// ---- bf16 helpers (storage-only; math fp32 / MFMA-fp32-accum) ----
struct __align__(8) us4 { unsigned short x, y, z, w; };

__device__ __forceinline__ float b2f(unsigned short u) {
    union { float f; unsigned v; } c; c.v = ((unsigned)u) << 16; return c.f;
}
__device__ __forceinline__ unsigned short f2b(float f) {
    union { float f; unsigned v; } c; c.f = f;
    return (unsigned short)((c.v + 0x7fffu + ((c.v >> 16) & 1u)) >> 16);
}

// ---------------------------------------------------------------- embed ----
__global__ __launch_bounds__(256) void embed_kernel(
    const float* __restrict__ x, const float* __restrict__ W,
    const float* __restrict__ b, unsigned short* __restrict__ h, int K)
{
    __shared__ float xs[256];            // 8 rows * K (K <= 32)
    const int m0 = blockIdx.x * 8;
    const int tid = threadIdx.x;
    if (tid < 8 * K) xs[tid] = x[(size_t)m0 * K + tid];
    __syncthreads();
    const int n = tid;
    float acc[8] = {0.f,0.f,0.f,0.f,0.f,0.f,0.f,0.f};
    for (int k = 0; k < K; ++k) {
        const float w = W[k * H_DIM + n];
        #pragma unroll
        for (int r = 0; r < 8; ++r) acc[r] += xs[r * K + k] * w;
    }
    const float bb = b[n];
    #pragma unroll
    for (int r = 0; r < 8; ++r)
        h[(size_t)(m0 + r) * H_DIM + n] = f2b(acc[r] + bb);
}

// ---------------------------------------------------------------- init v ---
__global__ __launch_bounds__(256) void init_v_kernel(
    const float* __restrict__ lig0, const float* __restrict__ prot0,
    float* __restrict__ lig_v, float* __restrict__ prot_v)
{
    const int b = blockIdx.x, n = threadIdx.x;
    lig_v[b * H_DIM + n]  = lig0[n];
    prot_v[b * H_DIM + n] = prot0[n];
}

// ------------------------------------------------- weight prep (W->Wt bf16)
__global__ __launch_bounds__(256) void wprep_kernel(
    const float* __restrict__ W, unsigned short* __restrict__ Wt)
{
    __shared__ float t[64][65];
    const int l = blockIdx.z;
    const int k0 = blockIdx.x * 64, n0 = blockIdx.y * 64;
    const int tid = threadIdx.x;
    const int c = tid & 63, r4 = tid >> 6;
    const float* Wl = W + (size_t)l * 65536;
    unsigned short* Wtl = Wt + (size_t)l * 65536;
    #pragma unroll
    for (int i = 0; i < 16; ++i) {
        const int r = i * 4 + r4;
        t[r][c] = Wl[(size_t)(k0 + r) * 256 + n0 + c];
    }
    __syncthreads();
    #pragma unroll
    for (int i = 0; i < 16; ++i) {
        const int n = i * 4 + r4;
        Wtl[(size_t)(n0 + n) * 256 + k0 + c] = f2b(t[c][n]);
    }
}

// ------------------------------------------------------- bucket build ------
__global__ __launch_bounds__(256) void bucket_build_kernel(
    const int* __restrict__ src, const int* __restrict__ dst, int E,
    int* __restrict__ deg, int* __restrict__ bucket,
    int* __restrict__ ovf, int* __restrict__ ovf_cnt)
{
    const int e = blockIdx.x * 256 + threadIdx.x;
    if (e >= E) return;
    const int d = dst[e], s = src[e];
    const int slot = atomicAdd(&deg[d], 1);
    if (slot < CAP) {
        bucket[(size_t)d * CAP + slot] = s;
    } else {
        const int o = atomicAdd(ovf_cnt, 1);
        if (o < OVF_CAP) { ovf[o * 2] = s; ovf[o * 2 + 1] = d; }
    }
}

// ------------------------------------------------------------ pool (v+=) ---
__global__ __launch_bounds__(256) void pool_add_kernel(
    const unsigned short* __restrict__ h, float* __restrict__ v, int cnt)
{
    const int b = blockIdx.x, n = threadIdx.x;
    const unsigned short* hp = &h[(size_t)b * cnt * H_DIM + n];
    float s = 0.f;
    #pragma unroll 8
    for (int r = 0; r < cnt; ++r) s += b2f(hp[(size_t)r * H_DIM]);
    v[b * H_DIM + n] += s;
}

// ----------------------------------------------------- small fp32 GEMM -----
template<bool RELU>
__global__ __launch_bounds__(256) void gemm_small_kernel(
    const float* __restrict__ A, const float* __restrict__ W,
    const float* __restrict__ bias, float* __restrict__ C,
    int M, int N, int K)
{
    constexpr int BM = 32, BN = 64, BK = 32, TM = 2;
    __shared__ __align__(16) float As[BK][BM + 4];
    __shared__ __align__(16) float Bs[BK][BN];
    const int tid = threadIdx.x;
    const int tx = tid & 15;
    const int ty = tid >> 4;
    const int m0 = blockIdx.x * BM;
    const int n0 = blockIdx.y * BN;

    float acc[TM][4] = {};

    for (int kt = 0; kt < K; kt += BK) {
        {
            const int row = tid >> 3, kq = tid & 7;
            const float4 a = *(const float4*)&A[(size_t)(m0 + row) * K + kt + kq * 4];
            As[kq * 4 + 0][row] = a.x;
            As[kq * 4 + 1][row] = a.y;
            As[kq * 4 + 2][row] = a.z;
            As[kq * 4 + 3][row] = a.w;
        }
        #pragma unroll
        for (int i = 0; i < 2; ++i) {
            const int f = tid + i * 256;
            const int row = f >> 4, c4 = f & 15;
            *(float4*)&Bs[row][c4 * 4] =
                *(const float4*)&W[(size_t)(kt + row) * N + n0 + c4 * 4];
        }
        __syncthreads();
        #pragma unroll
        for (int kk = 0; kk < BK; ++kk) {
            const float4 bv = *(const float4*)&Bs[kk][tx * 4];
            #pragma unroll
            for (int im = 0; im < TM; ++im) {
                const float a = As[kk][ty * TM + im];
                acc[im][0] += a * bv.x; acc[im][1] += a * bv.y;
                acc[im][2] += a * bv.z; acc[im][3] += a * bv.w;
            }
        }
        __syncthreads();
    }

    const float4 bb = *(const float4*)&bias[n0 + tx * 4];
    #pragma unroll
    for (int im = 0; im < TM; ++im) {
        const int m = m0 + ty * TM + im;
        float4 r;
        r.x = acc[im][0] + bb.x; r.y = acc[im][1] + bb.y;
        r.z = acc[im][2] + bb.z; r.w = acc[im][3] + bb.w;
        if constexpr (RELU) {
            r.x = fmaxf(r.x, 0.f); r.y = fmaxf(r.y, 0.f);
            r.z = fmaxf(r.z, 0.f); r.w = fmaxf(r.w, 0.f);
        }
        *(float4*)&C[(size_t)m * N + n0 + tx * 4] = r;
    }
}

// --------------------------------------------------- fused conv MFMA -------
// One kernel: t = relu(Z@W1+b1) (LDS tile), H[m] = (H[m]+v[batch[m]]) + t@W2+b2
// Z[M,256] bf16, Bt1/Bt2 [n][k] bf16. BM=64, BN=256 full width.
// 512 threads = 8 waves (2 x 4), wave tile 32x64. Block owns its 64 rows.
__global__ __launch_bounds__(512) void conv_fused_kernel(
    const unsigned short* __restrict__ Z,
    const unsigned short* __restrict__ Bt1, const float* __restrict__ b1,
    const unsigned short* __restrict__ Bt2, const float* __restrict__ b2,
    unsigned short* __restrict__ H, const float* __restrict__ v,
    const int* __restrict__ batch)
{
    constexpr int K = 256, BK = 32;
    __shared__ unsigned short As[64 * 32];       // 4 KB linear
    __shared__ unsigned short Bs[256 * 32];      // 16 KB linear
    __shared__ unsigned short Ts[64][264];       // 33 KB padded (t tile)
    const int tid  = threadIdx.x;
    const int lane = tid & 63;
    const int wid  = tid >> 6;
    const int wr   = wid >> 2;     // 0..1
    const int wc   = wid & 3;      // 0..3
    const int m0   = blockIdx.x * 64;
    const int albase = (tid & ~63) * 16;

    f32x4 acc[2][4];
    #pragma unroll
    for (int i = 0; i < 2; ++i)
        #pragma unroll
        for (int j = 0; j < 4; ++j) acc[i][j] = (f32x4){0.f, 0.f, 0.f, 0.f};

    // ---------------- GEMM1: Z @ W1 ----------------
    for (int kt = 0; kt < K; kt += BK) {
        if (tid < 256)   // A tile: 64x32 = 256 chunks (waves 0-3)
            __builtin_amdgcn_global_load_lds(
                (gas_ptr)&Z[(size_t)(m0 + (tid >> 2)) * K + kt + (tid & 3) * 8],
                (las_ptr)((char*)As + albase), 16, 0, 0);
        #pragma unroll
        for (int i = 0; i < 2; ++i) {   // B tile: 256x32 = 1024 chunks
            const int c = tid + i * 512;
            __builtin_amdgcn_global_load_lds(
                (gas_ptr)&Bt1[(size_t)(c >> 2) * K + kt + (c & 3) * 8],
                (las_ptr)((char*)Bs + albase + i * 8192), 16, 0, 0);
        }
        __syncthreads();
        short8 av[2], bv[4];
        #pragma unroll
        for (int mi = 0; mi < 2; ++mi)
            av[mi] = *(const short8*)&As[(wr * 32 + mi * 16 + (lane & 15)) * 32 + (lane >> 4) * 8];
        #pragma unroll
        for (int ni = 0; ni < 4; ++ni)
            bv[ni] = *(const short8*)&Bs[(wc * 64 + ni * 16 + (lane & 15)) * 32 + (lane >> 4) * 8];
        #pragma unroll
        for (int mi = 0; mi < 2; ++mi)
            #pragma unroll
            for (int ni = 0; ni < 4; ++ni)
                acc[mi][ni] = __builtin_amdgcn_mfma_f32_16x16x32_bf16(
                    av[mi], bv[ni], acc[mi][ni], 0, 0, 0);
        __syncthreads();
    }

    // bias + relu -> Ts (bf16)
    #pragma unroll
    for (int ni = 0; ni < 4; ++ni) {
        const int col = wc * 64 + ni * 16 + (lane & 15);
        const float bb = b1[col];
        #pragma unroll
        for (int mi = 0; mi < 2; ++mi)
            #pragma unroll
            for (int j = 0; j < 4; ++j) {
                const int row = wr * 32 + mi * 16 + ((lane >> 4) << 2) + j;
                Ts[row][col] = f2b(fmaxf(acc[mi][ni][j] + bb, 0.f));
            }
    }
    #pragma unroll
    for (int i = 0; i < 2; ++i)
        #pragma unroll
        for (int j = 0; j < 4; ++j) acc[i][j] = (f32x4){0.f, 0.f, 0.f, 0.f};
    __syncthreads();

    // ---------------- GEMM2: Ts @ W2 ----------------
    for (int kt = 0; kt < K; kt += BK) {
        #pragma unroll
        for (int i = 0; i < 2; ++i) {
            const int c = tid + i * 512;
            __builtin_amdgcn_global_load_lds(
                (gas_ptr)&Bt2[(size_t)(c >> 2) * K + kt + (c & 3) * 8],
                (las_ptr)((char*)Bs + albase + i * 8192), 16, 0, 0);
        }
        __syncthreads();
        short8 av[2], bv[4];
        #pragma unroll
        for (int mi = 0; mi < 2; ++mi)
            av[mi] = *(const short8*)&Ts[wr * 32 + mi * 16 + (lane & 15)][kt + (lane >> 4) * 8];
        #pragma unroll
        for (int ni = 0; ni < 4; ++ni)
            bv[ni] = *(const short8*)&Bs[(wc * 64 + ni * 16 + (lane & 15)) * 32 + (lane >> 4) * 8];
        #pragma unroll
        for (int mi = 0; mi < 2; ++mi)
            #pragma unroll
            for (int ni = 0; ni < 4; ++ni)
                acc[mi][ni] = __builtin_amdgcn_mfma_f32_16x16x32_bf16(
                    av[mi], bv[ni], acc[mi][ni], 0, 0, 0);
        __syncthreads();
    }

    // ---------------- epilogue: H = (H + v[batch]) + acc + b2 ----------------
    #pragma unroll
    for (int mi = 0; mi < 2; ++mi)
        #pragma unroll
        for (int j = 0; j < 4; ++j) {
            const int row = m0 + wr * 32 + mi * 16 + ((lane >> 4) << 2) + j;
            const int bq = batch[row];
            const float* vrow = &v[(size_t)bq * H_DIM];
            #pragma unroll
            for (int ni = 0; ni < 4; ++ni) {
                const int col = wc * 64 + ni * 16 + (lane & 15);
                unsigned short* hp = &H[(size_t)row * H_DIM + col];
                const float hup = b2f(*hp) + vrow[col];
                *hp = f2b(hup + acc[mi][ni][j] + b2[col]);
            }
        }
}

// ------------------------------------------------------------- BN split ----
__global__ __launch_bounds__(256) void bn_part_kernel(
    const float* __restrict__ vtmp, float* __restrict__ part)
{
    const int g = blockIdx.x, n = threadIdx.x;   // 32 blocks x 32 rows
    float s = 0.f, s2 = 0.f;
    #pragma unroll 8
    for (int r = 0; r < 32; ++r) {
        const float x = vtmp[(size_t)(g * 32 + r) * H_DIM + n];
        s += x; s2 += x * x;
    }
    part[g * H_DIM + n] = s;
    part[32 * H_DIM + g * H_DIM + n] = s2;
}

__global__ __launch_bounds__(256) void bn_finalize_kernel(
    const float* __restrict__ part, const float* __restrict__ gamma,
    const float* __restrict__ beta, float* __restrict__ scale,
    float* __restrict__ shift)
{
    const int n = threadIdx.x;
    float s = 0.f, s2 = 0.f;
    #pragma unroll 8
    for (int g = 0; g < 32; ++g) {
        s  += part[g * H_DIM + n];
        s2 += part[32 * H_DIM + g * H_DIM + n];
    }
    const float mean = s * (1.f / BGRAPH);
    const float var  = s2 * (1.f / BGRAPH) - mean * mean;
    const float sc   = gamma[n] * rsqrtf(var + 1e-5f);
    scale[n] = sc;
    shift[n] = beta[n] - mean * sc;
}

__global__ __launch_bounds__(256) void bn_relu_kernel(
    const float* __restrict__ vtmp, const float* __restrict__ scale,
    const float* __restrict__ shift, float* __restrict__ v)
{
    const int idx = blockIdx.x * 256 + threadIdx.x;
    const int n = idx & 255;
    v[idx] = fmaxf(vtmp[idx] * scale[n] + shift[n], 0.f);
}

// ----------------------------------------------------------- gather --------
// z[m] = bf16( (h[m]+v[b_m]) + sum_src (h[src]+v[b_src]) )   (1 wave / node)
__global__ __launch_bounds__(256) void gather2_kernel(
    const unsigned short* __restrict__ h, const float* __restrict__ v,
    const int* __restrict__ batch, const int* __restrict__ deg,
    const int* __restrict__ bucket, unsigned short* __restrict__ z)
{
    const int m = blockIdx.x * 4 + (threadIdx.x >> 6);
    const int lane = threadIdx.x & 63;
    int cnt = deg[m]; if (cnt > CAP) cnt = CAP;
    const us4 hv = *(const us4*)&h[(size_t)m * H_DIM + lane * 4];
    const int bm = batch[m];
    const float4 vm = *(const float4*)&v[(size_t)bm * H_DIM + lane * 4];
    float4 acc = { b2f(hv.x) + vm.x, b2f(hv.y) + vm.y,
                   b2f(hv.z) + vm.z, b2f(hv.w) + vm.w };
    const int* bp = &bucket[(size_t)m * CAP];
    for (int i = 0; i < cnt; i += 4) {
        const int4 s4 = *(const int4*)&bp[i];
        const int rem = cnt - i;
        us4 a0, a1, a2, a3;
        int q0, q1, q2, q3;
        a0 = *(const us4*)&h[(size_t)s4.x * H_DIM + lane * 4];
        q0 = batch[s4.x];
        if (rem > 1) { a1 = *(const us4*)&h[(size_t)s4.y * H_DIM + lane * 4]; q1 = batch[s4.y]; }
        if (rem > 2) { a2 = *(const us4*)&h[(size_t)s4.z * H_DIM + lane * 4]; q2 = batch[s4.z]; }
        if (rem > 3) { a3 = *(const us4*)&h[(size_t)s4.w * H_DIM + lane * 4]; q3 = batch[s4.w]; }
        {
            const float4 w0 = *(const float4*)&v[(size_t)q0 * H_DIM + lane * 4];
            acc.x += b2f(a0.x) + w0.x; acc.y += b2f(a0.y) + w0.y;
            acc.z += b2f(a0.z) + w0.z; acc.w += b2f(a0.w) + w0.w;
        }
        if (rem > 1) {
            const float4 w1 = *(const float4*)&v[(size_t)q1 * H_DIM + lane * 4];
            acc.x += b2f(a1.x) + w1.x; acc.y += b2f(a1.y) + w1.y;
            acc.z += b2f(a1.z) + w1.z; acc.w += b2f(a1.w) + w1.w;
        }
        if (rem > 2) {
            const float4 w2 = *(const float4*)&v[(size_t)q2 * H_DIM + lane * 4];
            acc.x += b2f(a2.x) + w2.x; acc.y += b2f(a2.y) + w2.y;
            acc.z += b2f(a2.z) + w2.z; acc.w += b2f(a2.w) + w2.w;
        }
        if (rem > 3) {
            const float4 w3 = *(const float4*)&v[(size_t)q3 * H_DIM + lane * 4];
            acc.x += b2f(a3.x) + w3.x; acc.y += b2f(a3.y) + w3.y;
            acc.z += b2f(a3.z) + w3.z; acc.w += b2f(a3.w) + w3.w;
        }
    }
    us4 o = { f2b(acc.x), f2b(acc.y), f2b(acc.z), f2b(acc.w) };
    *(us4*)&z[(size_t)m * H_DIM + lane * 4] = o;
}

// --------------------------------------------- overflow (rare, serial) -----
__global__ __launch_bounds__(64) void overflow_kernel(
    const int* __restrict__ ovf, const int* __restrict__ ovf_cnt,
    const unsigned short* __restrict__ h, const float* __restrict__ v,
    const int* __restrict__ batch, unsigned short* __restrict__ z)
{
    int n = *ovf_cnt; if (n > OVF_CAP) n = OVF_CAP;
    const int lane = threadIdx.x;
    for (int i = 0; i < n; ++i) {
        const int s = ovf[i * 2], d = ovf[i * 2 + 1];
        const int bs = batch[s];
        const us4 sv = *(const us4*)&h[(size_t)s * H_DIM + lane * 4];
        const float4 vs = *(const float4*)&v[(size_t)bs * H_DIM + lane * 4];
        us4* zp = (us4*)&z[(size_t)d * H_DIM + lane * 4];
        us4 zv = *zp;
        zv.x = f2b(b2f(zv.x) + b2f(sv.x) + vs.x);
        zv.y = f2b(b2f(zv.y) + b2f(sv.y) + vs.y);
        zv.z = f2b(b2f(zv.z) + b2f(sv.z) + vs.z);
        zv.w = f2b(b2f(zv.w) + b2f(sv.w) + vs.w);
        *zp = zv;
        __builtin_amdgcn_s_waitcnt(0);  // keep sequential per iteration
    }
}

// ----------------------------------------------------- final mean pools ----
__global__ __launch_bounds__(256) void pool_final_kernel(
    const unsigned short* __restrict__ lig_h,
    const unsigned short* __restrict__ prot_h, float* __restrict__ comb)
{
    const int b = blockIdx.x, n = threadIdx.x;
    float s = 0.f;
    #pragma unroll 8
    for (int r = 0; r < 64; ++r) s += b2f(lig_h[(size_t)(b * 64 + r) * H_DIM + n]);
    comb[(size_t)b * 512 + n] = s * (1.f / 64.f);
    float s2 = 0.f;
    #pragma unroll 8
    for (int r = 0; r < 128; ++r) s2 += b2f(prot_h[(size_t)(b * 128 + r) * H_DIM + n]);
    comb[(size_t)b * 512 + 256 + n] = s2 * (1.f / 128.f);
}

// ------------------------------------------------------------ final dot ----
__global__ __launch_bounds__(256) void pred_final_kernel(
    const float* __restrict__ hidden, const float* __restrict__ W2,
    const float* __restrict__ b2, float* __restrict__ out)
{
    const int b = blockIdx.x, t = threadIdx.x;
    float p = hidden[(size_t)b * H_DIM + t] * W2[t];
    #pragma unroll
    for (int off = 32; off >= 1; off >>= 1) p += __shfl_down(p, off);
    __shared__ float red[4];
    if ((t & 63) == 0) red[t >> 6] = p;
    __syncthreads();
    if (t == 0) out[b] = red[0] + red[1] + red[2] + red[3] + b2[0];
}

// ===========================================================================
extern "C" void kernel_launch(void* const* d_in, const int* in_sizes, int n_in,
                              void* d_out, int out_size, void* d_ws, size_t ws_size,
                              hipStream_t stream)
{
    const int NL = 65536, NP = 131072, EL = 262144, EP = 524288;
    const int B = BGRAPH, H = H_DIM;

    const float* lig_x        = (const float*)d_in[0];
    const float* prot_x       = (const float*)d_in[1];
    const float* lig_embed_W  = (const float*)d_in[2];
    const float* lig_embed_b  = (const float*)d_in[3];
    const float* prot_embed_W = (const float*)d_in[4];
    const float* prot_embed_b = (const float*)d_in[5];
    const float* lig_virtual0 = (const float*)d_in[6];
    const float* prot_virtual0= (const float*)d_in[7];
    const float* lig_conv_W1  = (const float*)d_in[8];
    const float* lig_conv_b1  = (const float*)d_in[9];
    const float* lig_conv_W2  = (const float*)d_in[10];
    const float* lig_conv_b2  = (const float*)d_in[11];
    const float* lig_vmlp_W   = (const float*)d_in[12];
    const float* lig_vmlp_b   = (const float*)d_in[13];
    const float* lig_vmlp_g   = (const float*)d_in[14];
    const float* lig_vmlp_be  = (const float*)d_in[15];
    const float* prot_conv_W1 = (const float*)d_in[16];
    const float* prot_conv_b1 = (const float*)d_in[17];
    const float* prot_conv_W2 = (const float*)d_in[18];
    const float* prot_conv_b2 = (const float*)d_in[19];
    const float* prot_vmlp_W  = (const float*)d_in[20];
    const float* prot_vmlp_b  = (const float*)d_in[21];
    const float* prot_vmlp_g  = (const float*)d_in[22];
    const float* prot_vmlp_be = (const float*)d_in[23];
    const float* pred_W1      = (const float*)d_in[24];
    const float* pred_b1      = (const float*)d_in[25];
    const float* pred_W2      = (const float*)d_in[26];
    const float* pred_b2      = (const float*)d_in[27];
    const int* lig_batch      = (const int*)d_in[28];
    const int* prot_batch     = (const int*)d_in[29];
    const int* lig_ei         = (const int*)d_in[30];
    const int* prot_ei        = (const int*)d_in[31];

    // ---- workspace layout (~190 MB) ----
    float* ws = (float*)d_ws;
    float* lig_v  = ws;                        // B*H
    float* prot_v = lig_v  + (size_t)B * H;    // B*H
    float* vtmp   = prot_v + (size_t)B * H;    // B*H
    float* scale  = vtmp   + (size_t)B * H;    // H
    float* shift  = scale  + H;                // H
    float* part   = shift  + H;                // 2*32*H
    float* comb   = part   + 64 * H;           // B*2H
    float* hidden = comb   + (size_t)B * 2 * H;// B*H
    unsigned short* zbuf   = (unsigned short*)(hidden + (size_t)B * H); // NP*H bf16
    unsigned short* lig_h  = zbuf  + (size_t)NP * H;                    // NL*H bf16
    unsigned short* prot_h = lig_h + (size_t)NL * H;                    // NP*H bf16
    unsigned short* wt_lw1 = prot_h + (size_t)NP * H;   // 5*H*H bf16 each
    unsigned short* wt_lw2 = wt_lw1 + (size_t)NLAYER * H * H;
    unsigned short* wt_pw1 = wt_lw2 + (size_t)NLAYER * H * H;
    unsigned short* wt_pw2 = wt_pw1 + (size_t)NLAYER * H * H;
    int* deg_lig  = (int*)(wt_pw2 + (size_t)NLAYER * H * H); // NL
    int* deg_prot = deg_lig  + NL;                   // NP
    int* bkt_lig  = deg_prot + NP;                   // NL*CAP
    int* bkt_prot = bkt_lig  + (size_t)NL * CAP;     // NP*CAP
    int* ovf_lig  = bkt_prot + (size_t)NP * CAP;     // OVF_CAP*2
    int* ovf_prot = ovf_lig  + OVF_CAP * 2;          // OVF_CAP*2
    int* ovf_cnts = ovf_prot + OVF_CAP * 2;          // 2

    // ---- one-time-per-call prep ----
    hipMemsetAsync(deg_lig, 0, (size_t)(NL + NP) * sizeof(int), stream);
    hipMemsetAsync(ovf_cnts, 0, 2 * sizeof(int), stream);
    bucket_build_kernel<<<EL / 256, 256, 0, stream>>>(
        lig_ei, lig_ei + EL, EL, deg_lig, bkt_lig, ovf_lig, ovf_cnts);
    bucket_build_kernel<<<EP / 256, 256, 0, stream>>>(
        prot_ei, prot_ei + EP, EP, deg_prot, bkt_prot, ovf_prot, ovf_cnts + 1);
    wprep_kernel<<<dim3(4, 4, NLAYER), 256, 0, stream>>>(lig_conv_W1, wt_lw1);
    wprep_kernel<<<dim3(4, 4, NLAYER), 256, 0, stream>>>(lig_conv_W2, wt_lw2);
    wprep_kernel<<<dim3(4, 4, NLAYER), 256, 0, stream>>>(prot_conv_W1, wt_pw1);
    wprep_kernel<<<dim3(4, 4, NLAYER), 256, 0, stream>>>(prot_conv_W2, wt_pw2);

    // ---- embeddings ----
    embed_kernel<<<NL / 8, 256, 0, stream>>>(lig_x, lig_embed_W, lig_embed_b, lig_h, 26);
    embed_kernel<<<NP / 8, 256, 0, stream>>>(prot_x, prot_embed_W, prot_embed_b, prot_h, 20);
    init_v_kernel<<<B, 256, 0, stream>>>(lig_virtual0, prot_virtual0, lig_v, prot_v);

    auto layer = [&](unsigned short* h, int Nn, int cnt, float* v,
                     const float* vW, const float* vb, const float* vg, const float* vbe,
                     const unsigned short* Wt1, const float* b1,
                     const unsigned short* Wt2, const float* b2,
                     const int* batch, const int* deg, const int* bkt,
                     const int* ovf, const int* ovf_cnt) {
        pool_add_kernel<<<B, 256, 0, stream>>>(h, v, cnt);
        gemm_small_kernel<false><<<dim3(B / 32, 4), 256, 0, stream>>>(
            v, vW, vb, vtmp, B, H, H);
        bn_part_kernel<<<32, 256, 0, stream>>>(vtmp, part);
        bn_finalize_kernel<<<1, 256, 0, stream>>>(part, vg, vbe, scale, shift);
        bn_relu_kernel<<<B, 256, 0, stream>>>(vtmp, scale, shift, v);
        gather2_kernel<<<Nn / 4, 256, 0, stream>>>(h, v, batch, deg, bkt, zbuf);
        overflow_kernel<<<1, 64, 0, stream>>>(ovf, ovf_cnt, h, v, batch, zbuf);
        conv_fused_kernel<<<Nn / 64, 512, 0, stream>>>(
            zbuf, Wt1, b1, Wt2, b2, h, v, batch);
    };

    for (int i = 0; i < NLAYER; ++i) {
        const size_t wo = (size_t)i * H * H;
        const size_t bo = (size_t)i * H;
        layer(lig_h, NL, 64, lig_v,
              lig_vmlp_W + wo, lig_vmlp_b + bo, lig_vmlp_g + bo, lig_vmlp_be + bo,
              wt_lw1 + wo, lig_conv_b1 + bo, wt_lw2 + wo, lig_conv_b2 + bo,
              lig_batch, deg_lig, bkt_lig, ovf_lig, ovf_cnts);
        layer(prot_h, NP, 128, prot_v,
              prot_vmlp_W + wo, prot_vmlp_b + bo, prot_vmlp_g + bo, prot_vmlp_be + bo,
              wt_pw1 + wo, prot_conv_b1 + bo, wt_pw2 + wo, prot_conv_b2 + bo,
              prot_batch, deg_prot, bkt_prot, ovf_prot, ovf_cnts + 1);
    }

    // ---- readout ----
    pool_final_kernel<<<B, 256, 0, stream>>>(lig_h, prot_h, comb);
    gemm_small_kernel<true><<<dim3(B / 32, 4), 256, 0, stream>>>(
        comb, pred_W1, pred_b1, hidden, B, H, 2 * H);
    pred_final_kernel<<<B, 256, 0, stream>>>(hidden, pred_W2, pred_b2, (float*)d_out);
}